// Round 1
// baseline (564.792 us; speedup 1.0000x reference)
//
#include <hip/hip_runtime.h>
#include <hip/hip_bf16.h>
#include <math.h>

#define NH 8
#define L 512
#define DR 384
#define DP 128
#define DS 16
#define DCAT 1280
#define TJ 64

#define SCALE_SCALAR 0.25f
#define SCALE_POINT  0.23570226039551584f   // (4.5*4)^-0.5
#define SCALE_TOTAL  0.5773502691896258f    // 3^-0.5

typedef __bf16 bf16_t;
typedef bf16_t bf16x8 __attribute__((ext_vector_type(8)));
typedef float  f32x4v __attribute__((ext_vector_type(4)));

// ---------------------------------------------------------------------------
// k_prep: Wout (1280,384) fp32 -> WoutT (384,1280) bf16  (write-coalesced)
// ---------------------------------------------------------------------------
__global__ __launch_bounds__(256) void k_prep(const float* __restrict__ Wout,
                                              __hip_bfloat16* __restrict__ WoutT) {
    int g = blockIdx.x * 256 + threadIdx.x;   // g = n*1280 + k, exactly 491520 threads
    int n = g / 1280, k = g % 1280;
    WoutT[g] = __float2bfloat16(Wout[k * 384 + n]);
}

// ---------------------------------------------------------------------------
// k_proj: per 4 residue rows: all 6 projections + euclid transform of points
// ---------------------------------------------------------------------------
__global__ __launch_bounds__(256) void k_proj(
    const float* __restrict__ x, const float* __restrict__ r, const float* __restrict__ t,
    const float* __restrict__ Wq_s, const float* __restrict__ Wk_s, const float* __restrict__ Wv_s,
    const float* __restrict__ Wq_p, const float* __restrict__ Wk_p, const float* __restrict__ Wv_p,
    float* __restrict__ q_s, float* __restrict__ k_s, float* __restrict__ v_s,
    float* __restrict__ q_p, float* __restrict__ k_p, float* __restrict__ v_p) {
    __shared__ float xs[4][DR];
    __shared__ float praw[4][3][96];
    __shared__ float rt[4][12];
    const int tid = threadIdx.x;
    const int r0 = blockIdx.x * 4;

    for (int idx = tid; idx < 4 * DR; idx += 256) {
        int row = idx / DR, k = idx % DR;
        xs[row][k] = x[(size_t)(r0 + row) * DR + k];
    }
    if (tid < 48) {
        int row = tid / 12, c = tid % 12;
        rt[row][c] = (c < 9) ? r[(r0 + row) * 9 + c] : t[(r0 + row) * 3 + (c - 9)];
    }
    __syncthreads();

    for (int it = 0; it < 11; ++it) {
        int item = tid + it * 256;
        if (item < 4 * 672) {
            int row = item / 672, o = item % 672;
            const float* W; int col, ncol, kind;
            if (o < 384) { kind = o / 128; col = o % 128; ncol = 128;
                           W = (kind == 0) ? Wq_s : (kind == 1) ? Wk_s : Wv_s; }
            else { int o2 = o - 384; kind = 3 + o2 / 96; col = o2 % 96; ncol = 96;
                   W = (kind == 3) ? Wq_p : (kind == 4) ? Wk_p : Wv_p; }
            float acc = 0.f;
            for (int k = 0; k < DR; ++k) acc += xs[row][k] * W[k * ncol + col];
            int gl = r0 + row, b = gl >> 9, l = gl & 511;
            if (o < 384) {
                int n = col / 16, d = col % 16;
                float* dst = (kind == 0) ? q_s : (kind == 1) ? k_s : v_s;
                dst[((size_t)(b * NH + n) * L + l) * DS + d] = acc;
            } else {
                praw[row][kind - 3][col] = acc;
            }
        }
    }
    __syncthreads();
    // euclid: out_c = sum_k raw_k * r[k][c] + t_c
    for (int it = 0; it < 5; ++it) {
        int item = tid + it * 256;
        if (item < 4 * 3 * 96) {
            int row = item / 288, rem = item % 288, arr = rem / 96, o = rem % 96;
            int n = o / 12, pc = o % 12, p = pc / 3, c = pc % 3;
            float acc = rt[row][9 + c];
            for (int k = 0; k < 3; ++k) acc += praw[row][arr][n * 12 + p * 3 + k] * rt[row][k * 3 + c];
            int gl = r0 + row, b = gl >> 9, l = gl & 511;
            float* dst = (arr == 0) ? q_p : (arr == 1) ? k_p : v_p;
            dst[((size_t)(b * NH + n) * L + l) * 12 + pc] = acc;
        }
    }
}

// ---------------------------------------------------------------------------
// k_attn: fused per-(b,i) attention; streams e once; writes concat row (bf16)
// ---------------------------------------------------------------------------
__global__ __launch_bounds__(256) void k_attn(
    const float* __restrict__ e, const float* __restrict__ r, const float* __restrict__ t,
    const float* __restrict__ Wpb, const float* __restrict__ gamma,
    const float* __restrict__ q_s, const float* __restrict__ k_s, const float* __restrict__ v_s,
    const float* __restrict__ q_p, const float* __restrict__ k_p, const float* __restrict__ v_p,
    __hip_bfloat16* __restrict__ concat) {
    __shared__ __align__(16) float et[TJ * DP];    // e tile, xor-swizzled float4 groups
    __shared__ float pt[NH][TJ];                   // exp(logit) for this tile
    __shared__ __align__(16) float wpbT[NH][DP];
    __shared__ float qsl[NH][DS];
    __shared__ float qpl[NH][12];
    __shared__ float lsh[NH];
    __shared__ float gsh[NH];
    __shared__ __align__(16) float accp[NH][DP];
    __shared__ float osh[NH][12];
    __shared__ float o2sh[NH][12];
    __shared__ float rtsh[12];

    const int tid = threadIdx.x;
    const int bi = blockIdx.x;
    const int b = bi >> 9, i = bi & 511;
    const int lane = tid & 63, wv = tid >> 6;       // logit pass: j=lane, heads wv & wv+4
    const int d4 = tid & 31, jsub = tid >> 5;       // out_pair pass ownership

    for (int idx = tid; idx < NH * DP; idx += 256) {
        int n = idx >> 7, d = idx & 127;
        wpbT[n][d] = Wpb[d * NH + n];
    }
    if (tid < 128) { int n = tid >> 4, d = tid & 15; qsl[n][d] = q_s[((size_t)(b * NH + n) * L + i) * DS + d]; }
    else if (tid < 224) { int o = tid - 128; int n = o / 12, pc = o % 12; qpl[n][pc] = q_p[((size_t)(b * NH + n) * L + i) * 12 + pc]; }
    else if (tid < 232) { gsh[tid - 224] = gamma[tid - 224]; }
    else if (tid < 244) { int c = tid - 232; rtsh[c] = (c < 9) ? r[bi * 9 + c] : t[bi * 3 + (c - 9)]; }

    float lsum0 = 0.f, lsum1 = 0.f;
    float4 accPair[NH];
#pragma unroll
    for (int n = 0; n < NH; ++n) accPair[n] = make_float4(0.f, 0.f, 0.f, 0.f);
    float accS = 0.f, accP3 = 0.f;
    const int nS = tid >> 4, dSd = tid & 15;               // out_scalar item (tid<128)
    const int oP = tid - 128, nP = (oP < 96) ? oP / 12 : 0, pcP = (oP < 96) ? oP % 12 : 0;

    const float4* esrc = reinterpret_cast<const float4*>(e + (size_t)(b * L + i) * L * DP);

    for (int tile = 0; tile < L / TJ; ++tile) {
        const int j0 = tile * TJ;
        __syncthreads();   // previous tile fully consumed
        // --- stage e[b,i, j0:j0+64, :] -> LDS (xor-swizzled float4 groups) ---
#pragma unroll
        for (int s = 0; s < 8; ++s) {
            int f = tid + s * 256;
            int j = f >> 5, g = f & 31;
            float4 v = esrc[(size_t)(j0 + j) * 32 + g];
            reinterpret_cast<float4*>(et)[j * 32 + (g ^ (j & 31))] = v;
        }
        __syncthreads();
        // --- logits + exp for heads wv, wv+4 at column j = lane ---
        {
            const int j = lane, jj = j0 + lane;
            const int n0 = wv, n1 = wv + 4;
            const float4* row = reinterpret_cast<const float4*>(et) + j * 32;
            const float4* w0 = reinterpret_cast<const float4*>(&wpbT[n0][0]);
            const float4* w1 = reinterpret_cast<const float4*>(&wpbT[n1][0]);
            float b0 = 0.f, b1 = 0.f;
#pragma unroll 8
            for (int g = 0; g < 32; ++g) {
                float4 ev = row[g ^ (j & 31)];
                float4 a0 = w0[g], a1 = w1[g];
                b0 += ev.x * a0.x + ev.y * a0.y + ev.z * a0.z + ev.w * a0.w;
                b1 += ev.x * a1.x + ev.y * a1.y + ev.z * a1.z + ev.w * a1.w;
            }
            float s0 = 0.f, s1 = 0.f;
            const float4* ks0 = reinterpret_cast<const float4*>(k_s + ((size_t)(b * NH + n0) * L + jj) * DS);
            const float4* ks1 = reinterpret_cast<const float4*>(k_s + ((size_t)(b * NH + n1) * L + jj) * DS);
#pragma unroll
            for (int g = 0; g < 4; ++g) {
                float4 kv0 = ks0[g], kv1 = ks1[g];
                s0 += kv0.x * qsl[n0][g * 4 + 0] + kv0.y * qsl[n0][g * 4 + 1] + kv0.z * qsl[n0][g * 4 + 2] + kv0.w * qsl[n0][g * 4 + 3];
                s1 += kv1.x * qsl[n1][g * 4 + 0] + kv1.y * qsl[n1][g * 4 + 1] + kv1.z * qsl[n1][g * 4 + 2] + kv1.w * qsl[n1][g * 4 + 3];
            }
            float sq0 = 0.f, sq1 = 0.f;
            const float* kp0 = k_p + ((size_t)(b * NH + n0) * L + jj) * 12;
            const float* kp1 = k_p + ((size_t)(b * NH + n1) * L + jj) * 12;
#pragma unroll
            for (int pc = 0; pc < 12; ++pc) {
                float dd0 = qpl[n0][pc] - kp0[pc]; sq0 += dd0 * dd0;
                float dd1 = qpl[n1][pc] - kp1[pc]; sq1 += dd1 * dd1;
            }
            float lg0 = SCALE_TOTAL * (s0 * SCALE_SCALAR + b0 - 0.5f * SCALE_POINT * gsh[n0] * sq0);
            float lg1 = SCALE_TOTAL * (s1 * SCALE_SCALAR + b1 - 0.5f * SCALE_POINT * gsh[n1] * sq1);
            float p0 = __expf(lg0), p1 = __expf(lg1);
            pt[n0][j] = p0; pt[n1][j] = p1;
            lsum0 += p0; lsum1 += p1;
        }
        __syncthreads();
        // --- out_pair accumulation: thread owns (d4 group, jsub) ---
        {
            const float4* et4 = reinterpret_cast<const float4*>(et);
#pragma unroll
            for (int s = 0; s < 8; ++s) {
                int j = jsub * 8 + s;
                float4 ev = et4[j * 32 + (d4 ^ (j & 31))];
#pragma unroll
                for (int n = 0; n < NH; ++n) {
                    float p = pt[n][j];
                    accPair[n].x += p * ev.x; accPair[n].y += p * ev.y;
                    accPair[n].z += p * ev.z; accPair[n].w += p * ev.w;
                }
            }
        }
        // --- out_scalar / out_point accumulation ---
        if (tid < 128) {
            const float* vsp = v_s + ((size_t)(b * NH + nS) * L + j0) * DS + dSd;
#pragma unroll 8
            for (int j = 0; j < TJ; ++j) accS += pt[nS][j] * vsp[j * DS];
        } else if (tid < 224) {
            const float* vpp = v_p + ((size_t)(b * NH + nP) * L + j0) * 12 + pcP;
#pragma unroll 8
            for (int j = 0; j < TJ; ++j) accP3 += pt[nP][j] * vpp[j * 12];
        }
    }

    // --- reductions & epilogue ---
    for (int off = 32; off > 0; off >>= 1) { lsum0 += __shfl_xor(lsum0, off); lsum1 += __shfl_xor(lsum1, off); }
    __syncthreads();                      // all tile reads of et/pt finished
    if (lane == 0) { lsh[wv] = lsum0; lsh[wv + 4] = lsum1; }
    {
        float4* red = reinterpret_cast<float4*>(et);   // reuse et: [jsub][n][d4]
#pragma unroll
        for (int n = 0; n < NH; ++n) red[(jsub * NH + n) * 32 + d4] = accPair[n];
    }
    __syncthreads();
    {
        int n = tid >> 5, g = tid & 31;
        const float4* red = reinterpret_cast<const float4*>(et);
        float4 sum = make_float4(0.f, 0.f, 0.f, 0.f);
#pragma unroll
        for (int s = 0; s < 8; ++s) {
            float4 v = red[(s * NH + n) * 32 + g];
            sum.x += v.x; sum.y += v.y; sum.z += v.z; sum.w += v.w;
        }
        reinterpret_cast<float4*>(&accp[n][0])[g] = sum;
    }
    __syncthreads();
    __hip_bfloat16* crow = concat + (size_t)bi * DCAT;
    if (tid < 128) crow[nS * DS + dSd] = __float2bfloat16(accS / lsh[nS]);
    for (int idx = tid; idx < NH * DP; idx += 256) {
        int n = idx >> 7;
        crow[128 + idx] = __float2bfloat16(accp[n][idx & 127] / lsh[n]);
    }
    if (tid >= 128 && tid < 224) osh[nP][pcP] = accP3 / lsh[nP];
    __syncthreads();
    if (tid < 96) {   // inverse euclid: o_c = sum_k (op_k - t_k) * r[c][k]
        int n = tid / 12, pc = tid % 12, p = pc / 3, c = pc % 3;
        float oc = 0.f;
#pragma unroll
        for (int k = 0; k < 3; ++k) oc += (osh[n][p * 3 + k] - rtsh[9 + k]) * rtsh[c * 3 + k];
        crow[128 + 1024 + tid] = __float2bfloat16(oc);
        o2sh[n][pc] = oc;
    }
    __syncthreads();
    if (tid < 32) {
        int n = tid >> 2, p = tid & 3;
        float vx = o2sh[n][p * 3], vy = o2sh[n][p * 3 + 1], vz = o2sh[n][p * 3 + 2];
        crow[128 + 1024 + 96 + tid] = __float2bfloat16(sqrtf(vx * vx + vy * vy + vz * vz));
    }
}

// ---------------------------------------------------------------------------
// k_out: bf16 MFMA GEMM: out[1024,384] = concat[1024,1280] @ Wout + bout
//   A = concat (row-major M x K), B staged from WoutT (N x K) -> logical K x N
// ---------------------------------------------------------------------------
__global__ __launch_bounds__(256) void k_out(const __hip_bfloat16* __restrict__ A,
                                             const __hip_bfloat16* __restrict__ Bt,
                                             const float* __restrict__ bout,
                                             float* __restrict__ out) {
    __shared__ __align__(16) bf16_t At[64 * 40];
    __shared__ __align__(16) bf16_t Bs[64 * 40];
    const int tid = threadIdx.x;
    const int row0 = blockIdx.x * 64, col0 = blockIdx.y * 64;
    const int wv = tid >> 6, lane = tid & 63;
    f32x4v acc[4] = {};

    for (int k0 = 0; k0 < 1280; k0 += 32) {
        __syncthreads();
        {
            int rr = tid >> 2, q = tid & 3;
            *reinterpret_cast<int4*>(&At[rr * 40 + q * 8]) =
                *reinterpret_cast<const int4*>(&A[(size_t)(row0 + rr) * 1280 + k0 + q * 8]);
            *reinterpret_cast<int4*>(&Bs[rr * 40 + q * 8]) =
                *reinterpret_cast<const int4*>(&Bt[(size_t)(col0 + rr) * 1280 + k0 + q * 8]);
        }
        __syncthreads();
        const int m = lane & 15, kq = lane >> 4;
        bf16x8 af = *reinterpret_cast<const bf16x8*>(&At[(wv * 16 + m) * 40 + kq * 8]);
#pragma unroll
        for (int nt = 0; nt < 4; ++nt) {
            bf16x8 bfr = *reinterpret_cast<const bf16x8*>(&Bs[(nt * 16 + m) * 40 + kq * 8]);
            acc[nt] = __builtin_amdgcn_mfma_f32_16x16x32_bf16(af, bfr, acc[nt], 0, 0, 0);
        }
    }
    const int col_l = lane & 15, rbase = (lane >> 4) * 4;
#pragma unroll
    for (int nt = 0; nt < 4; ++nt) {
        int col = col0 + nt * 16 + col_l;
        float bo = bout[col];
#pragma unroll
        for (int rg = 0; rg < 4; ++rg) {
            int rowg = row0 + wv * 16 + rbase + rg;
            out[(size_t)rowg * 384 + col] = acc[nt][rg] + bo;
        }
    }
}

// ---------------------------------------------------------------------------
extern "C" void kernel_launch(void* const* d_in, const int* in_sizes, int n_in,
                              void* d_out, int out_size, void* d_ws, size_t ws_size,
                              hipStream_t stream) {
    const float* x     = (const float*)d_in[0];
    const float* e     = (const float*)d_in[1];
    const float* r     = (const float*)d_in[2];
    const float* t     = (const float*)d_in[3];
    const float* Wq_s  = (const float*)d_in[4];
    const float* Wk_s  = (const float*)d_in[5];
    const float* Wv_s  = (const float*)d_in[6];
    const float* Wpb   = (const float*)d_in[7];
    const float* Wq_p  = (const float*)d_in[8];
    const float* Wk_p  = (const float*)d_in[9];
    const float* Wv_p  = (const float*)d_in[10];
    const float* gamma = (const float*)d_in[11];
    const float* Wout  = (const float*)d_in[12];
    const float* bout  = (const float*)d_in[13];

    float* ws  = (float*)d_ws;
    float* q_s = ws + 0;
    float* k_s = ws + 131072;
    float* v_s = ws + 262144;
    float* q_p = ws + 393216;
    float* k_p = ws + 491520;
    float* v_p = ws + 589824;
    __hip_bfloat16* concat = (__hip_bfloat16*)((char*)d_ws + 2752512);  // 2*512*1280 bf16
    __hip_bfloat16* WoutT  = (__hip_bfloat16*)((char*)d_ws + 5373952);  // 384*1280 bf16
    float* out = (float*)d_out;

    hipLaunchKernelGGL(k_prep, dim3(1920), dim3(256), 0, stream, Wout, WoutT);
    hipLaunchKernelGGL(k_proj, dim3(256), dim3(256), 0, stream,
                       x, r, t, Wq_s, Wk_s, Wv_s, Wq_p, Wk_p, Wv_p,
                       q_s, k_s, v_s, q_p, k_p, v_p);
    hipLaunchKernelGGL(k_attn, dim3(1024), dim3(256), 0, stream,
                       e, r, t, Wpb, gamma, q_s, k_s, v_s, q_p, k_p, v_p, concat);
    hipLaunchKernelGGL(k_out, dim3(16, 6), dim3(256), 0, stream, concat, WoutT, bout, out);
}